// Round 7
// baseline (205.809 us; speedup 1.0000x reference)
//
#include <hip/hip_runtime.h>
#include <math.h>

#define D 64
#define C 22
#define NCHUNK 64           // == wave width: one chunk-min per lane in loss
#define CHUNK 256           // NCHUNK*CHUNK covers Nt=16384; INF-padded otherwise
#define SPT 2               // students per thread in nn role
#define TLP 24              // padded logit row (6 x float4)
#define SMEMF 1440          // max(C*D + C, 4*CHUNK) floats
#define TEMP_F 2.0f
#define KL_W_F 0.2f

// Shared helpers — single source of these expressions so nn-role staging,
// tc4 prep, and loss-recovery compile to bit-identical chains.
__device__ __forceinline__ float4 prep_t(float x, float y, float z) {
    return make_float4(-2.f * x, -2.f * y, -2.f * z, fmaf(x, x, fmaf(y, y, z * z)));
}
__device__ __forceinline__ float dist_t(float sx, float sy, float sz,
                                        float tx, float ty, float tz, float tw) {
    // |t|^2 - 2 s.t   (|s|^2 constant per student: same argmin)
    return fmaf(sx, tx, fmaf(sy, ty, fmaf(sz, tz, tw)));
}

// ---------------------------------------------------------------- logits role body
__device__ __forceinline__ void logits_role(
        const float* __restrict__ feat, const float* __restrict__ W,
        const float* __restrict__ bias, float* __restrict__ olog,
        float* smem, int row0, int N)
{
    float* w = smem;                                   // C*D floats
    float* b = smem + C * D;
    for (int k = threadIdx.x; k < C * D; k += 256) w[k] = W[k];
    if (threadIdx.x < C) b[threadIdx.x] = bias[threadIdx.x];
    __syncthreads();

    int i = row0 + threadIdx.x;
    if (i >= N) return;

    float4 f[D / 4];
    const float4* fr = reinterpret_cast<const float4*>(feat + (size_t)i * D);
#pragma unroll
    for (int k = 0; k < D / 4; ++k) f[k] = fr[k];

    float* row = olog + (size_t)i * TLP;
#pragma unroll
    for (int c = 0; c < C; ++c) {
        float a = b[c];
        const float4* wr = reinterpret_cast<const float4*>(&w[c * D]);
#pragma unroll
        for (int k = 0; k < D / 4; ++k) {
            float4 wv = wr[k];
            a = fmaf(f[k].x, wv.x, a);
            a = fmaf(f[k].y, wv.y, a);
            a = fmaf(f[k].z, wv.z, a);
            a = fmaf(f[k].w, wv.w, a);
        }
        row[c] = a;
    }
}

// ================================================================ fat kernel
// role by blockIdx.x:  [0, nn_total)            -> 1-NN chunk minima (no index)
//                      [nn_total, +ntb)         -> teacher logits + tc4 prep
//                      [nn_total+ntb, +nsb)     -> student logits
__global__ void __launch_bounds__(256) fat_kernel(
        const float* __restrict__ sc,      // [Ns][3]
        const float* __restrict__ tc,      // [Nt][3]
        const float* __restrict__ t_feat,  // [Nt][D]
        const float* __restrict__ s_feat,  // [Ns][D]
        const float* __restrict__ Wt, const float* __restrict__ bt,
        const float* __restrict__ Ws, const float* __restrict__ bs_,
        float*  __restrict__ cand_d,       // [NCHUNK][Ns]  chunk-major
        float4* __restrict__ tc4,          // [Nt] prepped (-2x,-2y,-2z,|t|^2)
        float*  __restrict__ tlog,         // [Nt][TLP]
        float*  __restrict__ slog,         // [Ns][TLP]
        float*  __restrict__ acc, unsigned* __restrict__ ct,
        int Ns, int Nt, int nn_total, int ntb)
{
    __shared__ __align__(16) float smem[SMEMF];
    const int bx = blockIdx.x;

    if (bx == 0 && threadIdx.x == 0) { acc[0] = 0.f; acc[1] = 0.f; *ct = 0u; }

    if (bx < nn_total) {
        // ---------------- 1-NN role: chunk-min only, SoA LDS ----------------
        float* xs = smem;
        float* ys = smem + CHUNK;
        float* zs = smem + 2 * CHUNK;
        float* ws = smem + 3 * CHUNK;
        const int chunk = bx & (NCHUNK - 1);
        const int sub   = bx >> 6;                     // log2(NCHUNK)
        const int base  = chunk * CHUNK;

        if (threadIdx.x < CHUNK) {
            int j = threadIdx.x;
            int g = base + j;
            float4 p;
            if (g < Nt) p = prep_t(tc[(size_t)g * 3 + 0], tc[(size_t)g * 3 + 1],
                                   tc[(size_t)g * 3 + 2]);
            else        p = make_float4(0.f, 0.f, 0.f, INFINITY);
            xs[j] = p.x; ys[j] = p.y; zs[j] = p.z; ws[j] = p.w;
        }
        __syncthreads();

        const int i0 = sub * (256 * SPT) + threadIdx.x;
        float sx[SPT], sy[SPT], sz[SPT], best[SPT];
#pragma unroll
        for (int s = 0; s < SPT; ++s) {
            int i = i0 + s * 256;
            sx[s] = 0.f; sy[s] = 0.f; sz[s] = 0.f; best[s] = INFINITY;
            if (i < Ns) {
                sx[s] = sc[(size_t)i * 3 + 0];
                sy[s] = sc[(size_t)i * 3 + 1];
                sz[s] = sc[(size_t)i * 3 + 2];
            }
        }

#pragma unroll 4
        for (int j = 0; j < CHUNK; j += 4) {
            float4 X = *reinterpret_cast<const float4*>(&xs[j]);   // uniform addr:
            float4 Y = *reinterpret_cast<const float4*>(&ys[j]);   // LDS broadcast
            float4 Z = *reinterpret_cast<const float4*>(&zs[j]);
            float4 W = *reinterpret_cast<const float4*>(&ws[j]);
#pragma unroll
            for (int s = 0; s < SPT; ++s) {
                float d0 = dist_t(sx[s], sy[s], sz[s], X.x, Y.x, Z.x, W.x);
                float d1 = dist_t(sx[s], sy[s], sz[s], X.y, Y.y, Z.y, W.y);
                float d2 = dist_t(sx[s], sy[s], sz[s], X.z, Y.z, Z.z, W.z);
                float d3 = dist_t(sx[s], sy[s], sz[s], X.w, Y.w, Z.w, W.w);
                // right-nested: fuses to exactly 2 x v_min3_f32
                best[s] = fminf(d0, fminf(d1, fminf(d2, fminf(d3, best[s]))));
            }
        }
#pragma unroll
        for (int s = 0; s < SPT; ++s) {
            int i = i0 + s * 256;
            if (i < Ns) cand_d[(size_t)chunk * Ns + i] = best[s];
        }
    } else if (bx < nn_total + ntb) {
        // teacher logits + tc4 prep
        int i = (bx - nn_total) * 256 + threadIdx.x;
        if (i < Nt)
            tc4[i] = prep_t(tc[(size_t)i * 3 + 0], tc[(size_t)i * 3 + 1],
                            tc[(size_t)i * 3 + 2]);
        logits_role(t_feat, Wt, bt, tlog, smem, (bx - nn_total) * 256, Nt);
    } else {
        logits_role(s_feat, Ws, bs_, slog, smem, (bx - nn_total - ntb) * 256, Ns);
    }
}

// ================================================================ loss (+finalize)
// ONE WAVE PER STUDENT (16384 waves). Phase 1: lane k holds chunk k's min,
// lexicographic (val,k) butterfly. Phase 2: 64 lanes scan the 256-entry
// winning chunk (bit-equality). Phase 3: lane 0 does the 22-class math.
__global__ void __launch_bounds__(256) loss_kernel(
        const float* __restrict__ sc,       // [Ns][3]
        const int*   __restrict__ segment,  // [Ns]
        const float* __restrict__ tlog,     // [Nt][TLP]
        const float* __restrict__ slog,     // [Ns][TLP]
        const float* __restrict__ cand_d,   // [NCHUNK][Ns]
        const float4* __restrict__ tc4,     // [Nt]
        float* __restrict__ acc, unsigned* __restrict__ ct,
        float* __restrict__ out, int Ns)
{
    __shared__ float rs[4], rk[4];
    const int lane = threadIdx.x & 63;
    const int wv   = threadIdx.x >> 6;
    const int i    = blockIdx.x * 4 + wv;          // one student per wave

    float seg_i = 0.f, kl_i = 0.f;

    if (i < Ns) {
        // ---- phase 1: cross-lane argmin over 64 chunk minima
        float v = cand_d[(size_t)lane * Ns + i];
        int   k = lane;
#pragma unroll
        for (int off = 32; off; off >>= 1) {
            float vo = __shfl_xor(v, off);
            int   ko = __shfl_xor(k, off);
            bool take = (vo < v) || (vo == v && ko < k);   // first-chunk ties
            v = take ? vo : v;
            k = take ? ko : k;
        }

        // ---- phase 2: recover within-chunk index (bit-identical recompute)
        float sx = sc[(size_t)i * 3 + 0];
        float sy = sc[(size_t)i * 3 + 1];
        float sz = sc[(size_t)i * 3 + 2];
        const float4* P = tc4 + (size_t)k * CHUNK;
        int fj = 0x7fffffff;
#pragma unroll
        for (int t = 0; t < CHUNK / 64; ++t) {
            int j = lane + t * 64;                 // coalesced float4 across wave
            float4 p = P[j];
            float d = dist_t(sx, sy, sz, p.x, p.y, p.z, p.w);
            if (d == v && j < fj) fj = j;
        }
#pragma unroll
        for (int off = 32; off; off >>= 1)
            fj = min(fj, __shfl_xor(fj, off));
        if (fj == 0x7fffffff) fj = 0;              // unreachable fallback
        const int bidx = k * CHUNK + fj;

        // ---- phase 3: lane 0 does the 22-class CE + KL
        if (lane == 0) {
            float tt[TLP], ll[TLP];
            const float4* tr = reinterpret_cast<const float4*>(tlog + (size_t)bidx * TLP);
            const float4* sr = reinterpret_cast<const float4*>(slog + (size_t)i * TLP);
#pragma unroll
            for (int q = 0; q < TLP / 4; ++q) {
                reinterpret_cast<float4*>(tt)[q] = tr[q];
                reinterpret_cast<float4*>(ll)[q] = sr[q];
            }
            float m1 = ll[0], mt = tt[0];
#pragma unroll
            for (int c = 1; c < C; ++c) { m1 = fmaxf(m1, ll[c]); mt = fmaxf(mt, tt[c]); }

            // kl_row = [sum_c u_c*0.5*((t_c-mt)-(l_c-m1))]/U + lse2 - log U
            int sg = segment[i];
            float sum1 = 0.f, sum2 = 0.f, U = 0.f, T = 0.f, lsg = 0.f;
#pragma unroll
            for (int c = 0; c < C; ++c) {
                float dlc = ll[c] - m1;
                sum1 += expf(dlc);
                sum2 += expf(0.5f * dlc);
                if (c == sg) lsg = dlc;
                float du = tt[c] - mt;
                float u = expf(0.5f * du);
                U += u;
                T = fmaf(u, 0.5f * (du - dlc), T);
            }
            seg_i = logf(sum1) - lsg;
            kl_i  = T / U + logf(sum2) - logf(U);
        }
    }

    // ---- block reduce (lane 0 of each wave holds the values)
    if (lane == 0) { rs[wv] = seg_i; rk[wv] = kl_i; }
    __syncthreads();
    if (threadIdx.x == 0) {
        atomicAdd(&acc[0], rs[0] + rs[1] + rs[2] + rs[3]);
        atomicAdd(&acc[1], rk[0] + rk[1] + rk[2] + rk[3]);
        __threadfence();
        unsigned t = atomicAdd(ct, 1u);
        if (t == gridDim.x - 1) {
            float seg = atomicAdd(&acc[0], 0.f);   // coherent read
            float kl  = atomicAdd(&acc[1], 0.f);
            float seg_loss = seg / (float)Ns;
            float kl_loss  = KL_W_F * (kl / (float)Ns) * TEMP_F * TEMP_F;
            out[0] = seg_loss + kl_loss;
            out[1] = seg_loss;
            out[2] = kl_loss;
        }
    }
}

extern "C" void kernel_launch(void* const* d_in, const int* in_sizes, int n_in,
                              void* d_out, int out_size, void* d_ws, size_t ws_size,
                              hipStream_t stream)
{
    const float* s_feat  = (const float*)d_in[0];
    const float* t_feat  = (const float*)d_in[1];
    const float* s_coord = (const float*)d_in[2];
    const float* t_coord = (const float*)d_in[3];
    const float* seg_W   = (const float*)d_in[4];
    const float* seg_b   = (const float*)d_in[5];
    const float* seg_tW  = (const float*)d_in[6];
    const float* seg_tb  = (const float*)d_in[7];
    const int*   segment = (const int*)d_in[8];
    float* out = (float*)d_out;

    const int Ns = in_sizes[0] / D;
    const int Nt = in_sizes[1] / D;

    float*  tlog   = (float*)d_ws;                                    // [Nt*TLP]
    float*  slog   = tlog + (size_t)Nt * TLP;                         // [Ns*TLP]
    float*  cand_d = slog + (size_t)Ns * TLP;                         // [NCHUNK*Ns]
    float4* tc4    = (float4*)(cand_d + (size_t)NCHUNK * Ns);         // [Nt]
    float*  acc    = (float*)(tc4 + Nt);                              // [2]
    unsigned* ct   = (unsigned*)(acc + 2);

    const int subs     = (Ns + 256 * SPT - 1) / (256 * SPT);          // 32
    const int nn_total = subs * NCHUNK;                               // 2048
    const int ntb      = (Nt + 255) / 256;                            // 64
    const int nsb      = (Ns + 255) / 256;                            // 64

    fat_kernel<<<nn_total + ntb + nsb, 256, 0, stream>>>(
        s_coord, t_coord, t_feat, s_feat, seg_tW, seg_tb, seg_W, seg_b,
        cand_d, tc4, tlog, slog, acc, ct, Ns, Nt, nn_total, ntb);

    const int ls_b = (Ns + 3) / 4;                                    // wave/student
    loss_kernel<<<ls_b, 256, 0, stream>>>(
        s_coord, segment, tlog, slog, cand_d, tc4, acc, ct, out, Ns);
}

// Round 8
// 75.662 us; speedup vs baseline: 2.7201x; 2.7201x over previous
//
#include <hip/hip_runtime.h>
#include <math.h>

#define D 64
#define C 22
#define NCHUNK 64           // == wave width: one chunk-min per lane in loss
#define CHUNK 256           // NCHUNK*CHUNK covers Nt=16384; INF-padded otherwise
#define SPT 4               // students per thread in nn role
#define TLP 24              // padded logit row (6 x float4)
#define SMEMF 1440          // max(C*D + C, 4*CHUNK) floats
#define TEMP_F 2.0f
#define KL_W_F 0.2f

// Shared helpers — single source of these expressions so nn-role staging,
// tc4 prep, and loss-recovery compile to bit-identical chains.
__device__ __forceinline__ float4 prep_t(float x, float y, float z) {
    return make_float4(-2.f * x, -2.f * y, -2.f * z, fmaf(x, x, fmaf(y, y, z * z)));
}
__device__ __forceinline__ float dist_t(float sx, float sy, float sz,
                                        float tx, float ty, float tz, float tw) {
    // |t|^2 - 2 s.t   (|s|^2 constant per student: same argmin)
    return fmaf(sx, tx, fmaf(sy, ty, fmaf(sz, tz, tw)));
}

// 32-lane-group butterflies (offs <=16 keep lanes 0..31 self-contained)
__device__ __forceinline__ float bfly_max32(float v) {
#pragma unroll
    for (int off = 16; off; off >>= 1) v = fmaxf(v, __shfl_xor(v, off));
    return v;
}
__device__ __forceinline__ float bfly_sum32(float v) {
#pragma unroll
    for (int off = 16; off; off >>= 1) v += __shfl_xor(v, off);
    return v;
}

// ---------------------------------------------------------------- logits role body
__device__ __forceinline__ void logits_role(
        const float* __restrict__ feat, const float* __restrict__ W,
        const float* __restrict__ bias, float* __restrict__ olog,
        float* smem, int row0, int N)
{
    float* w = smem;                                   // C*D floats
    float* b = smem + C * D;
    for (int k = threadIdx.x; k < C * D; k += 256) w[k] = W[k];
    if (threadIdx.x < C) b[threadIdx.x] = bias[threadIdx.x];
    __syncthreads();

    int i = row0 + threadIdx.x;
    if (i >= N) return;

    float4 f[D / 4];
    const float4* fr = reinterpret_cast<const float4*>(feat + (size_t)i * D);
#pragma unroll
    for (int k = 0; k < D / 4; ++k) f[k] = fr[k];

    float* row = olog + (size_t)i * TLP;
#pragma unroll
    for (int c = 0; c < C; ++c) {
        float a = b[c];
        const float4* wr = reinterpret_cast<const float4*>(&w[c * D]);
#pragma unroll
        for (int k = 0; k < D / 4; ++k) {
            float4 wv = wr[k];
            a = fmaf(f[k].x, wv.x, a);
            a = fmaf(f[k].y, wv.y, a);
            a = fmaf(f[k].z, wv.z, a);
            a = fmaf(f[k].w, wv.w, a);
        }
        row[c] = a;
    }
}

// ================================================================ fat kernel
// role by blockIdx.x:  [0, nn_total)            -> 1-NN chunk minima (no index)
//                      [nn_total, +ntb)         -> teacher logits + tc4 prep
//                      [nn_total+ntb, +nsb)     -> student logits
__global__ void __launch_bounds__(256) fat_kernel(
        const float* __restrict__ sc,      // [Ns][3]
        const float* __restrict__ tc,      // [Nt][3]
        const float* __restrict__ t_feat,  // [Nt][D]
        const float* __restrict__ s_feat,  // [Ns][D]
        const float* __restrict__ Wt, const float* __restrict__ bt,
        const float* __restrict__ Ws, const float* __restrict__ bs_,
        float*  __restrict__ cand_d,       // [Ns][NCHUNK]  STUDENT-major
        float4* __restrict__ tc4,          // [Nt] prepped (-2x,-2y,-2z,|t|^2)
        float*  __restrict__ tlog,         // [Nt][TLP]
        float*  __restrict__ slog,         // [Ns][TLP]
        float*  __restrict__ acc, unsigned* __restrict__ ct,
        int Ns, int Nt, int nn_total, int ntb)
{
    __shared__ __align__(16) float smem[SMEMF];
    const int bx = blockIdx.x;

    if (bx == 0 && threadIdx.x == 0) { acc[0] = 0.f; acc[1] = 0.f; *ct = 0u; }

    if (bx < nn_total) {
        // ---------------- 1-NN role: chunk-min only, SoA LDS ----------------
        float* xs = smem;
        float* ys = smem + CHUNK;
        float* zs = smem + 2 * CHUNK;
        float* ws = smem + 3 * CHUNK;
        const int chunk = bx & (NCHUNK - 1);
        const int sub   = bx >> 6;                     // log2(NCHUNK)
        const int base  = chunk * CHUNK;

        if (threadIdx.x < CHUNK) {
            int j = threadIdx.x;
            int g = base + j;
            float4 p;
            if (g < Nt) p = prep_t(tc[(size_t)g * 3 + 0], tc[(size_t)g * 3 + 1],
                                   tc[(size_t)g * 3 + 2]);
            else        p = make_float4(0.f, 0.f, 0.f, INFINITY);
            xs[j] = p.x; ys[j] = p.y; zs[j] = p.z; ws[j] = p.w;
        }
        __syncthreads();

        const int i0 = sub * (256 * SPT) + threadIdx.x;
        float sx[SPT], sy[SPT], sz[SPT], best[SPT];
#pragma unroll
        for (int s = 0; s < SPT; ++s) {
            int i = i0 + s * 256;
            sx[s] = 0.f; sy[s] = 0.f; sz[s] = 0.f; best[s] = INFINITY;
            if (i < Ns) {
                sx[s] = sc[(size_t)i * 3 + 0];
                sy[s] = sc[(size_t)i * 3 + 1];
                sz[s] = sc[(size_t)i * 3 + 2];
            }
        }

#pragma unroll 4
        for (int j = 0; j < CHUNK; j += 4) {
            float4 X = *reinterpret_cast<const float4*>(&xs[j]);   // uniform addr:
            float4 Y = *reinterpret_cast<const float4*>(&ys[j]);   // LDS broadcast
            float4 Z = *reinterpret_cast<const float4*>(&zs[j]);
            float4 W = *reinterpret_cast<const float4*>(&ws[j]);
#pragma unroll
            for (int s = 0; s < SPT; ++s) {
                float d0 = dist_t(sx[s], sy[s], sz[s], X.x, Y.x, Z.x, W.x);
                float d1 = dist_t(sx[s], sy[s], sz[s], X.y, Y.y, Z.y, W.y);
                float d2 = dist_t(sx[s], sy[s], sz[s], X.z, Y.z, Z.z, W.z);
                float d3 = dist_t(sx[s], sy[s], sz[s], X.w, Y.w, Z.w, W.w);
                // right-nested: fuses to 2 x v_min3_f32
                best[s] = fminf(d0, fminf(d1, fminf(d2, fminf(d3, best[s]))));
            }
        }
#pragma unroll
        for (int s = 0; s < SPT; ++s) {
            int i = i0 + s * 256;
            if (i < Ns) cand_d[(size_t)i * NCHUNK + chunk] = best[s];
        }
    } else if (bx < nn_total + ntb) {
        // teacher logits + tc4 prep
        int i = (bx - nn_total) * 256 + threadIdx.x;
        if (i < Nt)
            tc4[i] = prep_t(tc[(size_t)i * 3 + 0], tc[(size_t)i * 3 + 1],
                            tc[(size_t)i * 3 + 2]);
        logits_role(t_feat, Wt, bt, tlog, smem, (bx - nn_total) * 256, Nt);
    } else {
        logits_role(s_feat, Ws, bs_, slog, smem, (bx - nn_total - ntb) * 256, Ns);
    }
}

// ================================================================ loss (+finalize)
// Wave per student iteration, grid-stride (512 blocks x 4 waves = 2048 waves,
// 8 students each). Phase 1: coalesced 256B read of the student's 64 chunk
// minima + lexicographic butterfly. Phase 2: 64-lane scan of winning chunk
// (bit-identical recompute). Phase 3: CLASS-PARALLEL math on lanes 0..21.
__global__ void __launch_bounds__(256) loss_kernel(
        const float* __restrict__ sc,       // [Ns][3]
        const int*   __restrict__ segment,  // [Ns]
        const float* __restrict__ tlog,     // [Nt][TLP]
        const float* __restrict__ slog,     // [Ns][TLP]
        const float* __restrict__ cand_d,   // [Ns][NCHUNK]
        const float4* __restrict__ tc4,     // [Nt]
        float* __restrict__ acc, unsigned* __restrict__ ct,
        float* __restrict__ out, int Ns)
{
    __shared__ float rs[4], rk[4];
    const int lane   = threadIdx.x & 63;
    const int wv     = threadIdx.x >> 6;
    const int nwaves = gridDim.x * 4;

    float seg_a = 0.f, kl_a = 0.f;

    for (int i = blockIdx.x * 4 + wv; i < Ns; i += nwaves) {
        // ---- phase 1: coalesced chunk-min row + cross-lane argmin
        float v = cand_d[(size_t)i * NCHUNK + lane];
        int   k = lane;
#pragma unroll
        for (int off = 32; off; off >>= 1) {
            float vo = __shfl_xor(v, off);
            int   ko = __shfl_xor(k, off);
            bool take = (vo < v) || (vo == v && ko < k);   // first-chunk ties
            v = take ? vo : v;
            k = take ? ko : k;
        }

        // ---- phase 2: recover within-chunk index (bit-identical recompute)
        float sx = sc[(size_t)i * 3 + 0];
        float sy = sc[(size_t)i * 3 + 1];
        float sz = sc[(size_t)i * 3 + 2];
        const float4* P = tc4 + (size_t)k * CHUNK;
        int fj = 0x7fffffff;
#pragma unroll
        for (int t = 0; t < CHUNK / 64; ++t) {
            int j = lane + t * 64;                 // coalesced float4 across wave
            float4 p = P[j];
            float d = dist_t(sx, sy, sz, p.x, p.y, p.z, p.w);
            if (d == v && j < fj) fj = j;
        }
#pragma unroll
        for (int off = 32; off; off >>= 1)
            fj = min(fj, __shfl_xor(fj, off));
        if (fj == 0x7fffffff) fj = 0;              // unreachable fallback
        const int bidx = k * CHUNK + fj;

        // ---- phase 3: class-parallel CE + KL (lanes 0..21)
        float lv = -INFINITY, tv = -INFINITY;
        if (lane < C) {
            lv = slog[(size_t)i * TLP + lane];
            tv = tlog[(size_t)bidx * TLP + lane];
        }
        float m1 = bfly_max32(lv);
        float mt = bfly_max32(tv);

        float dlc = lv - m1;                       // lane >= C: -INF (never read)
        float e1 = 0.f, e2 = 0.f, u = 0.f, Tc = 0.f;
        if (lane < C) {
            e1 = expf(dlc);
            e2 = expf(0.5f * dlc);
            float du = tv - mt;
            u  = expf(0.5f * du);
            Tc = u * 0.5f * (du - dlc);
        }
        float sum1 = bfly_sum32(e1);
        float sum2 = bfly_sum32(e2);
        float U    = bfly_sum32(u);
        float T    = bfly_sum32(Tc);
        int   sg   = segment[i];
        float lsg  = __shfl(dlc, sg);              // broadcast from lane sg

        // valid on lanes 0..31; harvested from lane 0 only
        seg_a += logf(sum1) - lsg;
        kl_a  += T / U + logf(sum2) - logf(U);
    }

    // ---- block reduce from each wave's lane 0, one atomic pair per block
    if (lane == 0) { rs[wv] = seg_a; rk[wv] = kl_a; }
    __syncthreads();
    if (threadIdx.x == 0) {
        atomicAdd(&acc[0], rs[0] + rs[1] + rs[2] + rs[3]);
        atomicAdd(&acc[1], rk[0] + rk[1] + rk[2] + rk[3]);
        __threadfence();
        unsigned t = atomicAdd(ct, 1u);
        if (t == gridDim.x - 1) {
            float seg = atomicAdd(&acc[0], 0.f);   // coherent read
            float kl  = atomicAdd(&acc[1], 0.f);
            float seg_loss = seg / (float)Ns;
            float kl_loss  = KL_W_F * (kl / (float)Ns) * TEMP_F * TEMP_F;
            out[0] = seg_loss + kl_loss;
            out[1] = seg_loss;
            out[2] = kl_loss;
        }
    }
}

extern "C" void kernel_launch(void* const* d_in, const int* in_sizes, int n_in,
                              void* d_out, int out_size, void* d_ws, size_t ws_size,
                              hipStream_t stream)
{
    const float* s_feat  = (const float*)d_in[0];
    const float* t_feat  = (const float*)d_in[1];
    const float* s_coord = (const float*)d_in[2];
    const float* t_coord = (const float*)d_in[3];
    const float* seg_W   = (const float*)d_in[4];
    const float* seg_b   = (const float*)d_in[5];
    const float* seg_tW  = (const float*)d_in[6];
    const float* seg_tb  = (const float*)d_in[7];
    const int*   segment = (const int*)d_in[8];
    float* out = (float*)d_out;

    const int Ns = in_sizes[0] / D;
    const int Nt = in_sizes[1] / D;

    float*  tlog   = (float*)d_ws;                                    // [Nt*TLP]
    float*  slog   = tlog + (size_t)Nt * TLP;                         // [Ns*TLP]
    float*  cand_d = slog + (size_t)Ns * TLP;                         // [Ns*NCHUNK]
    float4* tc4    = (float4*)(cand_d + (size_t)Ns * NCHUNK);         // [Nt]
    float*  acc    = (float*)(tc4 + Nt);                              // [2]
    unsigned* ct   = (unsigned*)(acc + 2);

    const int subs     = (Ns + 256 * SPT - 1) / (256 * SPT);          // 16
    const int nn_total = subs * NCHUNK;                               // 1024
    const int ntb      = (Nt + 255) / 256;                            // 64
    const int nsb      = (Ns + 255) / 256;                            // 64

    fat_kernel<<<nn_total + ntb + nsb, 256, 0, stream>>>(
        s_coord, t_coord, t_feat, s_feat, seg_tW, seg_tb, seg_W, seg_b,
        cand_d, tc4, tlog, slog, acc, ct, Ns, Nt, nn_total, ntb);

    loss_kernel<<<512, 256, 0, stream>>>(
        s_coord, segment, tlog, slog, cand_d, tc4, acc, ct, out, Ns);
}

// Round 9
// 65.943 us; speedup vs baseline: 3.1210x; 1.1474x over previous
//
#include <hip/hip_runtime.h>
#include <math.h>

#define D 64
#define C 22
#define NCHUNK 64           // == wave width: one chunk-min per lane in loss
#define CHUNK 256           // NCHUNK*CHUNK covers Nt=16384; INF-padded otherwise
#define SPT 8               // students per thread in nn role
#define TLP 24              // padded logit row (6 x float4)
#define SMEMF 1440          // max(C*D + C, 4*CHUNK) floats
#define TEMP_F 2.0f
#define KL_W_F 0.2f

// Shared helpers — single source of these expressions so nn-role staging,
// tc4 prep, and loss-recovery compile to bit-identical chains.
__device__ __forceinline__ float4 prep_t(float x, float y, float z) {
    return make_float4(-2.f * x, -2.f * y, -2.f * z, fmaf(x, x, fmaf(y, y, z * z)));
}
__device__ __forceinline__ float dist_t(float sx, float sy, float sz,
                                        float tx, float ty, float tz, float tw) {
    // |t|^2 - 2 s.t   (|s|^2 constant per student: same argmin)
    return fmaf(sx, tx, fmaf(sy, ty, fmaf(sz, tz, tw)));
}

// 32-lane-group butterflies (offs <=16 keep lanes 0..31 self-contained)
__device__ __forceinline__ float bfly_max32(float v) {
#pragma unroll
    for (int off = 16; off; off >>= 1) v = fmaxf(v, __shfl_xor(v, off));
    return v;
}
__device__ __forceinline__ float bfly_sum32(float v) {
#pragma unroll
    for (int off = 16; off; off >>= 1) v += __shfl_xor(v, off);
    return v;
}

// ---------------------------------------------------------------- logits role body
__device__ __forceinline__ void logits_role(
        const float* __restrict__ feat, const float* __restrict__ W,
        const float* __restrict__ bias, float* __restrict__ olog,
        float* smem, int row0, int N)
{
    float* w = smem;                                   // C*D floats
    float* b = smem + C * D;
    for (int k = threadIdx.x; k < C * D; k += 256) w[k] = W[k];
    if (threadIdx.x < C) b[threadIdx.x] = bias[threadIdx.x];
    __syncthreads();

    int i = row0 + threadIdx.x;
    if (i >= N) return;

    float4 f[D / 4];
    const float4* fr = reinterpret_cast<const float4*>(feat + (size_t)i * D);
#pragma unroll
    for (int k = 0; k < D / 4; ++k) f[k] = fr[k];

    float* row = olog + (size_t)i * TLP;
#pragma unroll
    for (int c = 0; c < C; ++c) {
        float a = b[c];
        const float4* wr = reinterpret_cast<const float4*>(&w[c * D]);
#pragma unroll
        for (int k = 0; k < D / 4; ++k) {
            float4 wv = wr[k];
            a = fmaf(f[k].x, wv.x, a);
            a = fmaf(f[k].y, wv.y, a);
            a = fmaf(f[k].z, wv.z, a);
            a = fmaf(f[k].w, wv.w, a);
        }
        row[c] = a;
    }
}

// ================================================================ fat kernel
// role by blockIdx.x:  [0, nn_total)            -> 1-NN chunk minima (no index)
//                      [nn_total, +ntb)         -> teacher logits + tc4 prep
//                      [nn_total+ntb, +nsb)     -> student logits
__global__ void __launch_bounds__(256) fat_kernel(
        const float* __restrict__ sc,      // [Ns][3]
        const float* __restrict__ tc,      // [Nt][3]
        const float* __restrict__ t_feat,  // [Nt][D]
        const float* __restrict__ s_feat,  // [Ns][D]
        const float* __restrict__ Wt, const float* __restrict__ bt,
        const float* __restrict__ Ws, const float* __restrict__ bs_,
        float*  __restrict__ cand_d,       // [Ns][NCHUNK]  student-major
        float4* __restrict__ tc4,          // [Nt] prepped (-2x,-2y,-2z,|t|^2)
        float*  __restrict__ tlog,         // [Nt][TLP]
        float*  __restrict__ slog,         // [Ns][TLP]
        float*  __restrict__ acc, unsigned* __restrict__ ct,
        int Ns, int Nt, int nn_total, int ntb)
{
    __shared__ __align__(16) float smem[SMEMF];
    const int bx = blockIdx.x;

    if (bx == 0 && threadIdx.x == 0) { acc[0] = 0.f; acc[1] = 0.f; *ct = 0u; }

    if (bx < nn_total) {
        // ---------------- 1-NN role: chunk-min only, SoA LDS ----------------
        float* xs = smem;
        float* ys = smem + CHUNK;
        float* zs = smem + 2 * CHUNK;
        float* ws = smem + 3 * CHUNK;
        const int chunk = bx & (NCHUNK - 1);
        const int sub   = bx >> 6;                     // log2(NCHUNK)
        const int base  = chunk * CHUNK;

        if (threadIdx.x < CHUNK) {
            int j = threadIdx.x;
            int g = base + j;
            float4 p;
            if (g < Nt) p = prep_t(tc[(size_t)g * 3 + 0], tc[(size_t)g * 3 + 1],
                                   tc[(size_t)g * 3 + 2]);
            else        p = make_float4(0.f, 0.f, 0.f, INFINITY);
            xs[j] = p.x; ys[j] = p.y; zs[j] = p.z; ws[j] = p.w;
        }
        __syncthreads();

        const int i0 = sub * (256 * SPT) + threadIdx.x;
        float sx[SPT], sy[SPT], sz[SPT], best[SPT];
#pragma unroll
        for (int s = 0; s < SPT; ++s) {
            int i = i0 + s * 256;
            sx[s] = 0.f; sy[s] = 0.f; sz[s] = 0.f; best[s] = INFINITY;
            if (i < Ns) {
                sx[s] = sc[(size_t)i * 3 + 0];
                sy[s] = sc[(size_t)i * 3 + 1];
                sz[s] = sc[(size_t)i * 3 + 2];
            }
        }

#pragma unroll 2
        for (int j = 0; j < CHUNK; j += 4) {
            float4 X = *reinterpret_cast<const float4*>(&xs[j]);   // uniform addr:
            float4 Y = *reinterpret_cast<const float4*>(&ys[j]);   // LDS broadcast
            float4 Z = *reinterpret_cast<const float4*>(&zs[j]);
            float4 W = *reinterpret_cast<const float4*>(&ws[j]);
#pragma unroll
            for (int s = 0; s < SPT; ++s) {
                float d0 = dist_t(sx[s], sy[s], sz[s], X.x, Y.x, Z.x, W.x);
                float d1 = dist_t(sx[s], sy[s], sz[s], X.y, Y.y, Z.y, W.y);
                float d2 = dist_t(sx[s], sy[s], sz[s], X.z, Y.z, Z.z, W.z);
                float d3 = dist_t(sx[s], sy[s], sz[s], X.w, Y.w, Z.w, W.w);
                // right-nested: fuses to 2 x v_min3_f32
                best[s] = fminf(d0, fminf(d1, fminf(d2, fminf(d3, best[s]))));
            }
        }
#pragma unroll
        for (int s = 0; s < SPT; ++s) {
            int i = i0 + s * 256;
            if (i < Ns) cand_d[(size_t)i * NCHUNK + chunk] = best[s];
        }
    } else if (bx < nn_total + ntb) {
        // teacher logits + tc4 prep
        int i = (bx - nn_total) * 256 + threadIdx.x;
        if (i < Nt)
            tc4[i] = prep_t(tc[(size_t)i * 3 + 0], tc[(size_t)i * 3 + 1],
                            tc[(size_t)i * 3 + 2]);
        logits_role(t_feat, Wt, bt, tlog, smem, (bx - nn_total) * 256, Nt);
    } else {
        logits_role(s_feat, Ws, bs_, slog, smem, (bx - nn_total - ntb) * 256, Ns);
    }
}

// ================================================================ loss (+finalize)
// 512 blocks x 1024 threads = 8192 waves = 2 blocks/CU = FULL 32 waves/CU.
// Wave per student iteration (2 each). Phase 1: coalesced 256B chunk-min row
// + lexicographic butterfly. Phase 2: 64-lane scan of winning chunk
// (bit-identical recompute). Phase 3: class-parallel math on lanes 0..21.
__global__ void __launch_bounds__(1024) loss_kernel(
        const float* __restrict__ sc,       // [Ns][3]
        const int*   __restrict__ segment,  // [Ns]
        const float* __restrict__ tlog,     // [Nt][TLP]
        const float* __restrict__ slog,     // [Ns][TLP]
        const float* __restrict__ cand_d,   // [Ns][NCHUNK]
        const float4* __restrict__ tc4,     // [Nt]
        float* __restrict__ acc, unsigned* __restrict__ ct,
        float* __restrict__ out, int Ns)
{
    __shared__ float rs[16], rk[16];
    const int lane   = threadIdx.x & 63;
    const int wv     = threadIdx.x >> 6;              // 0..15
    const int nwaves = gridDim.x * 16;

    float seg_a = 0.f, kl_a = 0.f;

    for (int i = blockIdx.x * 16 + wv; i < Ns; i += nwaves) {
        // ---- phase 1: coalesced chunk-min row + cross-lane argmin
        float v = cand_d[(size_t)i * NCHUNK + lane];
        int   k = lane;
#pragma unroll
        for (int off = 32; off; off >>= 1) {
            float vo = __shfl_xor(v, off);
            int   ko = __shfl_xor(k, off);
            bool take = (vo < v) || (vo == v && ko < k);   // first-chunk ties
            v = take ? vo : v;
            k = take ? ko : k;
        }

        // ---- phase 2: recover within-chunk index (bit-identical recompute)
        float sx = sc[(size_t)i * 3 + 0];
        float sy = sc[(size_t)i * 3 + 1];
        float sz = sc[(size_t)i * 3 + 2];
        const float4* P = tc4 + (size_t)k * CHUNK;
        int fj = 0x7fffffff;
#pragma unroll
        for (int t = 0; t < CHUNK / 64; ++t) {
            int j = lane + t * 64;                 // coalesced float4 across wave
            float4 p = P[j];
            float d = dist_t(sx, sy, sz, p.x, p.y, p.z, p.w);
            if (d == v && j < fj) fj = j;
        }
#pragma unroll
        for (int off = 32; off; off >>= 1)
            fj = min(fj, __shfl_xor(fj, off));
        if (fj == 0x7fffffff) fj = 0;              // unreachable fallback
        const int bidx = k * CHUNK + fj;

        // ---- phase 3: class-parallel CE + KL (lanes 0..21)
        float lv = -INFINITY, tv = -INFINITY;
        if (lane < C) {
            lv = slog[(size_t)i * TLP + lane];
            tv = tlog[(size_t)bidx * TLP + lane];
        }
        float m1 = bfly_max32(lv);
        float mt = bfly_max32(tv);

        float dlc = lv - m1;                       // lane >= C: -INF (never read)
        float e1 = 0.f, e2 = 0.f, u = 0.f, Tc = 0.f;
        if (lane < C) {
            e1 = expf(dlc);
            e2 = expf(0.5f * dlc);
            float du = tv - mt;
            u  = expf(0.5f * du);
            Tc = u * 0.5f * (du - dlc);
        }
        float sum1 = bfly_sum32(e1);
        float sum2 = bfly_sum32(e2);
        float U    = bfly_sum32(u);
        float T    = bfly_sum32(Tc);
        int   sg   = segment[i];
        float lsg  = __shfl(dlc, sg);              // broadcast from lane sg

        // valid on lanes 0..31; harvested from lane 0 only
        seg_a += logf(sum1) - lsg;
        kl_a  += T / U + logf(sum2) - logf(U);
    }

    // ---- block reduce from each wave's lane 0, one atomic pair per block
    if (lane == 0) { rs[wv] = seg_a; rk[wv] = kl_a; }
    __syncthreads();
    if (threadIdx.x == 0) {
        float s = 0.f, kk = 0.f;
#pragma unroll
        for (int w = 0; w < 16; ++w) { s += rs[w]; kk += rk[w]; }
        atomicAdd(&acc[0], s);
        atomicAdd(&acc[1], kk);
        __threadfence();
        unsigned t = atomicAdd(ct, 1u);
        if (t == gridDim.x - 1) {
            float seg = atomicAdd(&acc[0], 0.f);   // coherent read
            float kl  = atomicAdd(&acc[1], 0.f);
            float seg_loss = seg / (float)Ns;
            float kl_loss  = KL_W_F * (kl / (float)Ns) * TEMP_F * TEMP_F;
            out[0] = seg_loss + kl_loss;
            out[1] = seg_loss;
            out[2] = kl_loss;
        }
    }
}

extern "C" void kernel_launch(void* const* d_in, const int* in_sizes, int n_in,
                              void* d_out, int out_size, void* d_ws, size_t ws_size,
                              hipStream_t stream)
{
    const float* s_feat  = (const float*)d_in[0];
    const float* t_feat  = (const float*)d_in[1];
    const float* s_coord = (const float*)d_in[2];
    const float* t_coord = (const float*)d_in[3];
    const float* seg_W   = (const float*)d_in[4];
    const float* seg_b   = (const float*)d_in[5];
    const float* seg_tW  = (const float*)d_in[6];
    const float* seg_tb  = (const float*)d_in[7];
    const int*   segment = (const int*)d_in[8];
    float* out = (float*)d_out;

    const int Ns = in_sizes[0] / D;
    const int Nt = in_sizes[1] / D;

    float*  tlog   = (float*)d_ws;                                    // [Nt*TLP]
    float*  slog   = tlog + (size_t)Nt * TLP;                         // [Ns*TLP]
    float*  cand_d = slog + (size_t)Ns * TLP;                         // [Ns*NCHUNK]
    float4* tc4    = (float4*)(cand_d + (size_t)Ns * NCHUNK);         // [Nt]
    float*  acc    = (float*)(tc4 + Nt);                              // [2]
    unsigned* ct   = (unsigned*)(acc + 2);

    const int subs     = (Ns + 256 * SPT - 1) / (256 * SPT);          // 8
    const int nn_total = subs * NCHUNK;                               // 512
    const int ntb      = (Nt + 255) / 256;                            // 64
    const int nsb      = (Ns + 255) / 256;                            // 64

    fat_kernel<<<nn_total + ntb + nsb, 256, 0, stream>>>(
        s_coord, t_coord, t_feat, s_feat, seg_tW, seg_tb, seg_W, seg_b,
        cand_d, tc4, tlog, slog, acc, ct, Ns, Nt, nn_total, ntb);

    loss_kernel<<<512, 1024, 0, stream>>>(
        s_coord, segment, tlog, slog, cand_d, tc4, acc, ct, out, Ns);
}